// Round 1
// baseline (386.966 us; speedup 1.0000x reference)
//
#include <hip/hip_runtime.h>
#include <hip/hip_bf16.h>

#define BB 32
#define LL 196
#define DD 512
#define HH 8
#define DHH 64
#define BL (BB*LL)   // 6272
#define PL 224       // padded L (K-dim of PV)
#define VSTR 232     // LDS stride for PL-wide rows

typedef __bf16 bf16x8 __attribute__((ext_vector_type(8)));
typedef float f32x4 __attribute__((ext_vector_type(4)));

#define MFMA16(a,b,c) __builtin_amdgcn_mfma_f32_16x16x32_bf16((a),(b),(c),0,0,0)

static __device__ __forceinline__ bf16x8 pack8(float4 v0, float4 v1) {
  bf16x8 o;
  o[0] = (__bf16)v0.x; o[1] = (__bf16)v0.y; o[2] = (__bf16)v0.z; o[3] = (__bf16)v0.w;
  o[4] = (__bf16)v1.x; o[5] = (__bf16)v1.y; o[6] = (__bf16)v1.z; o[7] = (__bf16)v1.w;
  return o;
}

// ---------------------------------------------------------------------------
// Projection: out[i][o] = sum_c X[i][c] * W[o][c] + bias[o]   (NT GEMM, bf16 out)
// grid (BL/64, DD/64), block 256
// ---------------------------------------------------------------------------
__global__ __launch_bounds__(256) void proj_kernel(
    const float* __restrict__ X, const float* __restrict__ W,
    const float* __restrict__ bias, __bf16* __restrict__ out)
{
  __shared__ __bf16 sA[64][72];
  __shared__ __bf16 sB[64][72];
  const int tid = threadIdx.x;
  const int w = tid >> 6, lane = tid & 63;
  const int wr = (w >> 1) * 32, wc = (w & 1) * 32;
  const int bm = blockIdx.x * 64, bn = blockIdx.y * 64;

  f32x4 acc[2][2] = {};
  const int r = tid >> 2, c0 = (tid & 3) * 16;

  for (int k0 = 0; k0 < DD; k0 += 64) {
    {
      const float* src = X + (size_t)(bm + r) * DD + k0 + c0;
      float4 v0 = ((const float4*)src)[0];
      float4 v1 = ((const float4*)src)[1];
      float4 v2 = ((const float4*)src)[2];
      float4 v3 = ((const float4*)src)[3];
      *(bf16x8*)&sA[r][c0]     = pack8(v0, v1);
      *(bf16x8*)&sA[r][c0 + 8] = pack8(v2, v3);
      const float* srcw = W + (size_t)(bn + r) * DD + k0 + c0;
      float4 w0 = ((const float4*)srcw)[0];
      float4 w1 = ((const float4*)srcw)[1];
      float4 w2 = ((const float4*)srcw)[2];
      float4 w3 = ((const float4*)srcw)[3];
      *(bf16x8*)&sB[r][c0]     = pack8(w0, w1);
      *(bf16x8*)&sB[r][c0 + 8] = pack8(w2, w3);
    }
    __syncthreads();
    #pragma unroll
    for (int kc = 0; kc < 2; ++kc) {
      const int kk = kc * 32 + (lane >> 4) * 8;
      bf16x8 a0 = *(const bf16x8*)&sA[wr + (lane & 15)][kk];
      bf16x8 a1 = *(const bf16x8*)&sA[wr + 16 + (lane & 15)][kk];
      bf16x8 b0 = *(const bf16x8*)&sB[wc + (lane & 15)][kk];
      bf16x8 b1 = *(const bf16x8*)&sB[wc + 16 + (lane & 15)][kk];
      acc[0][0] = MFMA16(a0, b0, acc[0][0]);
      acc[0][1] = MFMA16(a0, b1, acc[0][1]);
      acc[1][0] = MFMA16(a1, b0, acc[1][0]);
      acc[1][1] = MFMA16(a1, b1, acc[1][1]);
    }
    __syncthreads();
  }
  #pragma unroll
  for (int mt = 0; mt < 2; ++mt)
    #pragma unroll
    for (int nt = 0; nt < 2; ++nt)
      #pragma unroll
      for (int rr = 0; rr < 4; ++rr) {
        const int row = bm + wr + mt * 16 + (lane >> 4) * 4 + rr;
        const int col = bn + wc + nt * 16 + (lane & 15);
        out[(size_t)row * DD + col] = (__bf16)(acc[mt][nt][rr] + bias[col]);
      }
}

// ---------------------------------------------------------------------------
// Retrieve: per (a,b) block compute 196x196 scores = Qp[a]·Kp[b]^T (K=512),
// fused row-max-mean (t2v) + col-max-mean (v2t) -> one logit.
// grid (32,32), block 256
// ---------------------------------------------------------------------------
__global__ __launch_bounds__(256) void retrieve_kernel(
    const __bf16* __restrict__ qp, const __bf16* __restrict__ kp,
    const float* __restrict__ logit_scale, float* __restrict__ out_logits)
{
  __shared__ __bf16 sQ[64][72];
  __shared__ __bf16 sK[256][72];
  __shared__ float colmax[256];
  __shared__ float rowpart[4][64];
  __shared__ float red[8];

  const int a = blockIdx.x, b = blockIdx.y;
  const int tid = threadIdx.x;
  const int w = tid >> 6, lane = tid & 63;

  colmax[tid] = -1e30f;
  float t2v_acc = 0.f;
  __syncthreads();

  const int sr = tid >> 2, sc0 = (tid & 3) * 16;

  for (int strip = 0; strip < 4; ++strip) {
    f32x4 acc[4][4] = {};
    for (int k0 = 0; k0 < DD; k0 += 64) {
      {
        const int grow = strip * 64 + sr;
        uint4 z = make_uint4(0, 0, 0, 0);
        uint4 v0 = z, v1 = z;
        if (grow < LL) {
          const uint4* src = (const uint4*)(qp + (size_t)(a * LL + grow) * DD + k0 + sc0);
          v0 = src[0]; v1 = src[1];
        }
        *(uint4*)&sQ[sr][sc0]     = v0;
        *(uint4*)&sQ[sr][sc0 + 8] = v1;
      }
      #pragma unroll
      for (int p = 0; p < 4; ++p) {
        const int m = p * 64 + sr;
        uint4 z = make_uint4(0, 0, 0, 0);
        uint4 v0 = z, v1 = z;
        if (m < LL) {
          const uint4* src = (const uint4*)(kp + (size_t)(b * LL + m) * DD + k0 + sc0);
          v0 = src[0]; v1 = src[1];
        }
        *(uint4*)&sK[m][sc0]     = v0;
        *(uint4*)&sK[m][sc0 + 8] = v1;
      }
      __syncthreads();
      #pragma unroll
      for (int kc = 0; kc < 2; ++kc) {
        const int kk = kc * 32 + (lane >> 4) * 8;
        bf16x8 af[4], bfr[4];
        #pragma unroll
        for (int mt = 0; mt < 4; ++mt)
          af[mt] = *(const bf16x8*)&sQ[mt * 16 + (lane & 15)][kk];
        #pragma unroll
        for (int nt = 0; nt < 4; ++nt)
          bfr[nt] = *(const bf16x8*)&sK[w * 64 + nt * 16 + (lane & 15)][kk];
        #pragma unroll
        for (int mt = 0; mt < 4; ++mt)
          #pragma unroll
          for (int nt = 0; nt < 4; ++nt)
            acc[mt][nt] = MFMA16(af[mt], bfr[nt], acc[mt][nt]);
      }
      __syncthreads();
    }
    // row maxes over this wave's 64 cols
    #pragma unroll
    for (int mt = 0; mt < 4; ++mt) {
      #pragma unroll
      for (int rr = 0; rr < 4; ++rr) {
        float m = -1e30f;
        #pragma unroll
        for (int nt = 0; nt < 4; ++nt) {
          const int col = w * 64 + nt * 16 + (lane & 15);
          m = (col < LL) ? fmaxf(m, acc[mt][nt][rr]) : m;
        }
        m = fmaxf(m, __shfl_xor(m, 1));
        m = fmaxf(m, __shfl_xor(m, 2));
        m = fmaxf(m, __shfl_xor(m, 4));
        m = fmaxf(m, __shfl_xor(m, 8));
        if ((lane & 15) == 0) rowpart[w][mt * 16 + (lane >> 4) * 4 + rr] = m;
      }
    }
    // col maxes over this strip's valid rows
    #pragma unroll
    for (int nt = 0; nt < 4; ++nt) {
      float cm = -1e30f;
      #pragma unroll
      for (int mt = 0; mt < 4; ++mt)
        #pragma unroll
        for (int rr = 0; rr < 4; ++rr) {
          const int grow = strip * 64 + mt * 16 + (lane >> 4) * 4 + rr;
          cm = (grow < LL) ? fmaxf(cm, acc[mt][nt][rr]) : cm;
        }
      cm = fmaxf(cm, __shfl_xor(cm, 16));
      cm = fmaxf(cm, __shfl_xor(cm, 32));
      if (lane < 16) {
        const int col = w * 64 + nt * 16 + lane;
        colmax[col] = fmaxf(colmax[col], cm);
      }
    }
    __syncthreads();
    if (tid < 64) {
      const int grow = strip * 64 + tid;
      if (grow < LL) {
        float rm = fmaxf(fmaxf(rowpart[0][tid], rowpart[1][tid]),
                         fmaxf(rowpart[2][tid], rowpart[3][tid]));
        t2v_acc += rm;
      }
    }
    __syncthreads();
  }

  float vsum = (tid < LL) ? colmax[tid] : 0.f;
  #pragma unroll
  for (int o = 1; o < 64; o <<= 1) vsum += __shfl_xor(vsum, o);
  float tsum = t2v_acc;
  #pragma unroll
  for (int o = 1; o < 64; o <<= 1) tsum += __shfl_xor(tsum, o);
  if (lane == 0) { red[w] = vsum; red[4 + w] = tsum; }
  __syncthreads();
  if (tid == 0) {
    const float v2t = red[0] + red[1] + red[2] + red[3];
    const float t2v = red[4] + red[5] + red[6] + red[7];
    out_logits[a * BB + b] = expf(logit_scale[0]) * (t2v + v2t) * (0.5f / (float)LL);
  }
}

// ---------------------------------------------------------------------------
// Self-attention per (b,h): scores -> softmax -> probs-mean atomic -> PV -> ctx
// grid (32,8), block 256 (4 waves; wave handles strips of 16 query rows)
// ---------------------------------------------------------------------------
__global__ __launch_bounds__(256) void attn_kernel(
    const __bf16* __restrict__ qp, const __bf16* __restrict__ kp,
    const __bf16* __restrict__ vp, float* __restrict__ ctx,
    float* __restrict__ probs_out)
{
  __shared__ __bf16 vt[64][VSTR];        // V^T: vt[d][m]
  __shared__ __bf16 pr[4][16][VSTR];     // per-wave probs strip

  const int bb = blockIdx.x, h = blockIdx.y;
  const int tid = threadIdx.x;
  const int w = tid >> 6, lane = tid & 63;

  for (int m = w; m < PL; m += 4) {
    __bf16 v = (__bf16)0.f;
    if (m < LL) v = vp[(size_t)(bb * LL + m) * DD + h * DHH + lane];
    vt[lane][m] = v;
  }
  __syncthreads();

  for (int strip = w; strip < 13; strip += 4) {
    const int row0 = strip * 16;
    const int arow = row0 + (lane & 15);
    bf16x8 aq[2];
    #pragma unroll
    for (int kc = 0; kc < 2; ++kc) {
      bf16x8 z = {};
      aq[kc] = (arow < LL)
        ? *(const bf16x8*)&qp[(size_t)(bb * LL + arow) * DD + h * DHH + kc * 32 + (lane >> 4) * 8]
        : z;
    }
    f32x4 s[14] = {};
    #pragma unroll
    for (int nt = 0; nt < 14; ++nt) {
      const int brow = nt * 16 + (lane & 15);
      #pragma unroll
      for (int kc = 0; kc < 2; ++kc) {
        bf16x8 bk = {};
        if (brow < LL)
          bk = *(const bf16x8*)&kp[(size_t)(bb * LL + brow) * DD + h * DHH + kc * 32 + (lane >> 4) * 8];
        s[nt] = MFMA16(aq[kc], bk, s[nt]);
      }
    }
    const int colbase = lane & 15;
    #pragma unroll
    for (int nt = 0; nt < 14; ++nt) {
      const bool cv = (nt * 16 + colbase) < LL;
      #pragma unroll
      for (int rr = 0; rr < 4; ++rr)
        s[nt][rr] = cv ? s[nt][rr] * 0.125f : -1e30f;
    }
    float mx[4], dn[4];
    #pragma unroll
    for (int rr = 0; rr < 4; ++rr) {
      float m = s[0][rr];
      #pragma unroll
      for (int nt = 1; nt < 14; ++nt) m = fmaxf(m, s[nt][rr]);
      m = fmaxf(m, __shfl_xor(m, 1));
      m = fmaxf(m, __shfl_xor(m, 2));
      m = fmaxf(m, __shfl_xor(m, 4));
      m = fmaxf(m, __shfl_xor(m, 8));
      mx[rr] = m;
    }
    #pragma unroll
    for (int nt = 0; nt < 14; ++nt)
      #pragma unroll
      for (int rr = 0; rr < 4; ++rr)
        s[nt][rr] = __expf(s[nt][rr] - mx[rr]);
    #pragma unroll
    for (int rr = 0; rr < 4; ++rr) {
      float d = 0.f;
      #pragma unroll
      for (int nt = 0; nt < 14; ++nt) d += s[nt][rr];
      d += __shfl_xor(d, 1);
      d += __shfl_xor(d, 2);
      d += __shfl_xor(d, 4);
      d += __shfl_xor(d, 8);
      dn[rr] = 1.f / d;
    }
    #pragma unroll
    for (int nt = 0; nt < 14; ++nt) {
      const int col = nt * 16 + colbase;
      #pragma unroll
      for (int rr = 0; rr < 4; ++rr) {
        const float p = s[nt][rr] * dn[rr];
        const int qrow = row0 + (lane >> 4) * 4 + rr;
        pr[w][(lane >> 4) * 4 + rr][col] = (__bf16)p;
        if (qrow < LL && col < LL)
          atomicAdd(&probs_out[((size_t)bb * LL + qrow) * LL + col], p * 0.125f);
      }
    }
    asm volatile("s_waitcnt lgkmcnt(0)" ::: "memory");
    f32x4 c4[4] = {};
    #pragma unroll
    for (int kc = 0; kc < 7; ++kc) {
      bf16x8 ap = *(const bf16x8*)&pr[w][lane & 15][kc * 32 + (lane >> 4) * 8];
      #pragma unroll
      for (int dt = 0; dt < 4; ++dt) {
        bf16x8 bv = *(const bf16x8*)&vt[dt * 16 + (lane & 15)][kc * 32 + (lane >> 4) * 8];
        c4[dt] = MFMA16(ap, bv, c4[dt]);
      }
    }
    #pragma unroll
    for (int dt = 0; dt < 4; ++dt)
      #pragma unroll
      for (int rr = 0; rr < 4; ++rr) {
        const int qrow = row0 + (lane >> 4) * 4 + rr;
        if (qrow < LL)
          ctx[(size_t)(bb * LL + qrow) * DD + h * DHH + dt * 16 + (lane & 15)] = c4[dt][rr];
      }
  }
}

// ---------------------------------------------------------------------------
// Residual + LayerNorm, in-place on d_out's ctx region. One wave per row.
// ---------------------------------------------------------------------------
__global__ __launch_bounds__(256) void ln_kernel(
    float* __restrict__ ctx, const float* __restrict__ resid,
    const float* __restrict__ gamma, const float* __restrict__ beta)
{
  const int tid = threadIdx.x;
  const int w = tid >> 6, lane = tid & 63;
  const int row = blockIdx.x * 4 + w;
  float* crow = ctx + (size_t)row * DD;
  const float* rrow = resid + (size_t)row * DD;
  const int c = lane * 8;

  float4 a0 = *(const float4*)(crow + c);
  float4 a1 = *(const float4*)(crow + c + 4);
  float4 b0 = *(const float4*)(rrow + c);
  float4 b1 = *(const float4*)(rrow + c + 4);
  float v[8] = {a0.x + b0.x, a0.y + b0.y, a0.z + b0.z, a0.w + b0.w,
                a1.x + b1.x, a1.y + b1.y, a1.z + b1.z, a1.w + b1.w};

  float sum = 0.f;
  #pragma unroll
  for (int j = 0; j < 8; ++j) sum += v[j];
  #pragma unroll
  for (int o = 1; o < 64; o <<= 1) sum += __shfl_xor(sum, o);
  const float mu = sum * (1.f / (float)DD);

  float var = 0.f;
  #pragma unroll
  for (int j = 0; j < 8; ++j) { float d = v[j] - mu; var += d * d; }
  #pragma unroll
  for (int o = 1; o < 64; o <<= 1) var += __shfl_xor(var, o);
  const float rstd = rsqrtf(var * (1.f / (float)DD) + 1e-6f);

  float4 g0 = *(const float4*)(gamma + c);
  float4 g1 = *(const float4*)(gamma + c + 4);
  float4 e0 = *(const float4*)(beta + c);
  float4 e1 = *(const float4*)(beta + c + 4);
  float g[8] = {g0.x, g0.y, g0.z, g0.w, g1.x, g1.y, g1.z, g1.w};
  float e[8] = {e0.x, e0.y, e0.z, e0.w, e1.x, e1.y, e1.z, e1.w};

  float o_[8];
  #pragma unroll
  for (int j = 0; j < 8; ++j) o_[j] = (v[j] - mu) * rstd * g[j] + e[j];
  float4 w0 = make_float4(o_[0], o_[1], o_[2], o_[3]);
  float4 w1 = make_float4(o_[4], o_[5], o_[6], o_[7]);
  *(float4*)(crow + c) = w0;
  *(float4*)(crow + c + 4) = w1;
}

// ---------------------------------------------------------------------------
extern "C" void kernel_launch(void* const* d_in, const int* in_sizes, int n_in,
                              void* d_out, int out_size, void* d_ws, size_t ws_size,
                              hipStream_t stream)
{
  const float* xq    = (const float*)d_in[0];
  const float* xk    = (const float*)d_in[1];
  const float* xv    = (const float*)d_in[2];
  const float* Wq    = (const float*)d_in[3];
  const float* bq    = (const float*)d_in[4];
  const float* Wk    = (const float*)d_in[5];
  const float* bk    = (const float*)d_in[6];
  const float* Wv    = (const float*)d_in[7];
  const float* bv    = (const float*)d_in[8];
  const float* gamma = (const float*)d_in[9];
  const float* beta  = (const float*)d_in[10];
  const float* ls    = (const float*)d_in[11];

  float* out_ctx    = (float*)d_out;
  float* out_logits = out_ctx + (size_t)BL * DD;   // 3,211,264
  float* out_probs  = out_logits + BB * BB;        // +1,024

  __bf16* qp = (__bf16*)d_ws;
  __bf16* kp = qp + (size_t)BL * DD;
  __bf16* vp = kp + (size_t)BL * DD;

  hipMemsetAsync(out_probs, 0, (size_t)BB * LL * LL * sizeof(float), stream);

  dim3 pgrid(BL / 64, DD / 64);
  proj_kernel<<<pgrid, 256, 0, stream>>>(xq, Wq, bq, qp);
  proj_kernel<<<pgrid, 256, 0, stream>>>(xk, Wk, bk, kp);
  proj_kernel<<<pgrid, 256, 0, stream>>>(xv, Wv, bv, vp);

  retrieve_kernel<<<dim3(BB, BB), 256, 0, stream>>>(qp, kp, ls, out_logits);
  attn_kernel<<<dim3(BB, HH), 256, 0, stream>>>(qp, kp, vp, out_ctx, out_probs);
  ln_kernel<<<BL / 4, 256, 0, stream>>>(out_ctx, xq, gamma, beta);
}

// Round 2
// 301.284 us; speedup vs baseline: 1.2844x; 1.2844x over previous
//
#include <hip/hip_runtime.h>
#include <hip/hip_bf16.h>

#define BB 32
#define LL 196
#define DD 512
#define HH 8
#define DHH 64
#define BL (BB*LL)   // 6272
#define PVK 224      // padded m-dim for PV (7 * 32)
#define PSTR 236     // pr LDS stride (bf16)
#define ASTR 232     // pacc LDS stride (f32)

typedef __bf16 bf16x8 __attribute__((ext_vector_type(8)));
typedef float f32x4 __attribute__((ext_vector_type(4)));

#define MFMA16(a,b,c) __builtin_amdgcn_mfma_f32_16x16x32_bf16((a),(b),(c),0,0,0)

#define GLOAD_LDS16(g, l) __builtin_amdgcn_global_load_lds( \
    (const __attribute__((address_space(1))) void*)(g), \
    (__attribute__((address_space(3))) void*)(l), 16, 0, 0)

static __device__ __forceinline__ bf16x8 pack8(float4 v0, float4 v1) {
  bf16x8 o;
  o[0] = (__bf16)v0.x; o[1] = (__bf16)v0.y; o[2] = (__bf16)v0.z; o[3] = (__bf16)v0.w;
  o[4] = (__bf16)v1.x; o[5] = (__bf16)v1.y; o[6] = (__bf16)v1.z; o[7] = (__bf16)v1.w;
  return o;
}

static __device__ __forceinline__ unsigned fkey(float f) {
  unsigned u = __float_as_uint(f);
  return u ^ ((unsigned)((int)u >> 31) | 0x80000000u);
}
static __device__ __forceinline__ float unkey(unsigned k) {
  unsigned u = (k & 0x80000000u) ? (k ^ 0x80000000u) : ~k;
  return __uint_as_float(u);
}

// ---------------------------------------------------------------------------
// Fused QKV projection: out[i][o] = sum_c X[i][c] * W[o][c] + bias[o]
// grid (98, 8, 3), block 256
// ---------------------------------------------------------------------------
__global__ __launch_bounds__(256) void proj3_kernel(
    const float* __restrict__ xq, const float* __restrict__ xk, const float* __restrict__ xv,
    const float* __restrict__ Wq, const float* __restrict__ Wk, const float* __restrict__ Wv,
    const float* __restrict__ bq, const float* __restrict__ bk, const float* __restrict__ bv,
    __bf16* __restrict__ qp, __bf16* __restrict__ kp, __bf16* __restrict__ vp)
{
  __shared__ __bf16 sA[64][72];
  __shared__ __bf16 sB[64][72];

  const float* X; const float* W; const float* bias; __bf16* out;
  if (blockIdx.z == 0)      { X = xq; W = Wq; bias = bq; out = qp; }
  else if (blockIdx.z == 1) { X = xk; W = Wk; bias = bk; out = kp; }
  else                      { X = xv; W = Wv; bias = bv; out = vp; }

  const int tid = threadIdx.x;
  const int w = tid >> 6, lane = tid & 63;
  const int wr = (w >> 1) * 32, wc = (w & 1) * 32;
  const int bm = blockIdx.x * 64, bn = blockIdx.y * 64;

  f32x4 acc[2][2] = {};
  const int r = tid >> 2, c0 = (tid & 3) * 16;

  for (int k0 = 0; k0 < DD; k0 += 64) {
    {
      const float* src = X + (size_t)(bm + r) * DD + k0 + c0;
      float4 v0 = ((const float4*)src)[0];
      float4 v1 = ((const float4*)src)[1];
      float4 v2 = ((const float4*)src)[2];
      float4 v3 = ((const float4*)src)[3];
      *(bf16x8*)&sA[r][c0]     = pack8(v0, v1);
      *(bf16x8*)&sA[r][c0 + 8] = pack8(v2, v3);
      const float* srcw = W + (size_t)(bn + r) * DD + k0 + c0;
      float4 w0 = ((const float4*)srcw)[0];
      float4 w1 = ((const float4*)srcw)[1];
      float4 w2 = ((const float4*)srcw)[2];
      float4 w3 = ((const float4*)srcw)[3];
      *(bf16x8*)&sB[r][c0]     = pack8(w0, w1);
      *(bf16x8*)&sB[r][c0 + 8] = pack8(w2, w3);
    }
    __syncthreads();
    #pragma unroll
    for (int kc = 0; kc < 2; ++kc) {
      const int kk = kc * 32 + (lane >> 4) * 8;
      bf16x8 a0 = *(const bf16x8*)&sA[wr + (lane & 15)][kk];
      bf16x8 a1 = *(const bf16x8*)&sA[wr + 16 + (lane & 15)][kk];
      bf16x8 b0 = *(const bf16x8*)&sB[wc + (lane & 15)][kk];
      bf16x8 b1 = *(const bf16x8*)&sB[wc + 16 + (lane & 15)][kk];
      acc[0][0] = MFMA16(a0, b0, acc[0][0]);
      acc[0][1] = MFMA16(a0, b1, acc[0][1]);
      acc[1][0] = MFMA16(a1, b0, acc[1][0]);
      acc[1][1] = MFMA16(a1, b1, acc[1][1]);
    }
    __syncthreads();
  }
  #pragma unroll
  for (int mt = 0; mt < 2; ++mt)
    #pragma unroll
    for (int nt = 0; nt < 2; ++nt)
      #pragma unroll
      for (int rr = 0; rr < 4; ++rr) {
        const int row = bm + wr + mt * 16 + (lane >> 4) * 4 + rr;
        const int col = bn + wc + nt * 16 + (lane & 15);
        out[(size_t)row * DD + col] = (__bf16)(acc[mt][nt][rr] + bias[col]);
      }
}

// ---------------------------------------------------------------------------
// V transpose: vp[(bb*196+m)][h*64+d] -> vpT[(bb*8+h)*64+d][m], m padded to 224 w/ 0
// grid (256, 4), block 256
// ---------------------------------------------------------------------------
__global__ __launch_bounds__(256) void transpose_v_kernel(
    const __bf16* __restrict__ vp, __bf16* __restrict__ vpT)
{
  __shared__ __bf16 sT[64][72];
  const int bbh = blockIdx.x;        // bb*8 + h
  const int mt = blockIdx.y;         // m-tile of 64
  const int bb = bbh >> 3, h = bbh & 7;
  const int tid = threadIdx.x;
  {
    const int r = tid >> 2, c0 = (tid & 3) * 16;
    const int m = mt * 64 + r;
    bf16x8 z = {};
    bf16x8 v0 = z, v1 = z;
    if (m < LL) {
      const bf16x8* src = (const bf16x8*)&vp[(size_t)(bb * LL + m) * DD + h * DHH + c0];
      v0 = src[0]; v1 = src[1];
    }
    *(bf16x8*)&sT[r][c0]     = v0;
    *(bf16x8*)&sT[r][c0 + 8] = v1;
  }
  __syncthreads();
  {
    const int d = tid >> 2, mc0 = (tid & 3) * 16;
    if (mt * 64 + mc0 < PVK) {
      bf16x8 o0, o1;
      #pragma unroll
      for (int j = 0; j < 8; ++j) { o0[j] = sT[mc0 + j][d]; o1[j] = sT[mc0 + 8 + j][d]; }
      __bf16* dst = vpT + (size_t)(bbh * 64 + d) * PVK + mt * 64 + mc0;
      *(bf16x8*)dst = o0;
      *(bf16x8*)(dst + 8) = o1;
    }
  }
}

// ---------------------------------------------------------------------------
// Retrieve as flat 6272x6272x512 NT GEMM (m97 structure) + fused segment-max
// epilogue via atomicMax on monotone-keyed u32 tables.
// grid 2401 (1-D, swizzled), block 256
// ---------------------------------------------------------------------------
__global__ __launch_bounds__(256) void retrieve_kernel(
    const __bf16* __restrict__ qp, const __bf16* __restrict__ kp,
    unsigned* __restrict__ rmax, unsigned* __restrict__ cmax)
{
  __shared__ __bf16 sA[128 * 64];
  __shared__ __bf16 sB[128 * 64];

  // XCD-chunk (m204 bijective, q=300,r=1) then 7x7 supertile decode
  const int orig = blockIdx.x;
  const int xcd = orig & 7, idx = orig >> 3;
  const int wg = (xcd == 0) ? idx : (301 + (xcd - 1) * 300 + idx);
  const int st = wg / 49, wi = wg % 49;
  const int brow = ((st / 7) * 7 + wi / 7) * 128;
  const int bcol = ((st % 7) * 7 + wi % 7) * 128;

  const int tid = threadIdx.x;
  const int w = tid >> 6, lane = tid & 63;
  const int wr = (w >> 1) * 64, wc = (w & 1) * 64;

  f32x4 acc[4][4] = {};

  for (int k0 = 0; k0 < DD; k0 += 64) {
    const __bf16* aBase = qp + (size_t)brow * DD + k0;
    const __bf16* bBase = kp + (size_t)bcol * DD + k0;
    #pragma unroll
    for (int c = 0; c < 4; ++c) {
      const int p = c * 256 + tid;
      const int row = p >> 3, sl = p & 7;
      GLOAD_LDS16(aBase + (size_t)row * DD + sl * 8, sA + p * 8);
    }
    #pragma unroll
    for (int c = 0; c < 4; ++c) {
      const int p = c * 256 + tid;
      const int row = p >> 3, sl = p & 7;
      GLOAD_LDS16(bBase + (size_t)row * DD + sl * 8, sB + p * 8);
    }
    __syncthreads();
    #pragma unroll
    for (int kc = 0; kc < 2; ++kc) {
      const int kk = kc * 32 + (lane >> 4) * 8;
      bf16x8 af[4], bfr[4];
      #pragma unroll
      for (int mt = 0; mt < 4; ++mt)
        af[mt] = *(const bf16x8*)&sA[(wr + mt * 16 + (lane & 15)) * 64 + kk];
      #pragma unroll
      for (int nt = 0; nt < 4; ++nt)
        bfr[nt] = *(const bf16x8*)&sB[(wc + nt * 16 + (lane & 15)) * 64 + kk];
      #pragma unroll
      for (int mt = 0; mt < 4; ++mt)
        #pragma unroll
        for (int nt = 0; nt < 4; ++nt)
          acc[mt][nt] = MFMA16(af[mt], bfr[nt], acc[mt][nt]);
    }
    __syncthreads();
  }

  // Row-max per 196-col segment (t2v path)
  const int wcol0 = bcol + wc;
  const int wrow0 = brow + wr;
  {
    const int b0 = wcol0 / LL, b1 = (wcol0 + 63) / LL;
    for (int b = b0; b <= b1; ++b) {
      const int lo = b * LL, hi = lo + LL;
      #pragma unroll
      for (int mt = 0; mt < 4; ++mt)
        #pragma unroll
        for (int rr = 0; rr < 4; ++rr) {
          float m = -3e38f;
          #pragma unroll
          for (int nt = 0; nt < 4; ++nt) {
            const int col = wcol0 + nt * 16 + (lane & 15);
            if (col >= lo && col < hi) m = fmaxf(m, acc[mt][nt][rr]);
          }
          m = fmaxf(m, __shfl_xor(m, 1));
          m = fmaxf(m, __shfl_xor(m, 2));
          m = fmaxf(m, __shfl_xor(m, 4));
          m = fmaxf(m, __shfl_xor(m, 8));
          if ((lane & 15) == 0) {
            const int grow = wrow0 + mt * 16 + (lane >> 4) * 4 + rr;
            atomicMax(&rmax[(size_t)grow * BB + b], fkey(m));
          }
        }
    }
  }
  // Col-max per 196-row segment (v2t path)
  {
    const int a0 = wrow0 / LL, a1 = (wrow0 + 63) / LL;
    for (int a = a0; a <= a1; ++a) {
      const int lo = a * LL, hi = lo + LL;
      #pragma unroll
      for (int nt = 0; nt < 4; ++nt) {
        float cm = -3e38f;
        #pragma unroll
        for (int mt = 0; mt < 4; ++mt)
          #pragma unroll
          for (int rr = 0; rr < 4; ++rr) {
            const int grow = wrow0 + mt * 16 + (lane >> 4) * 4 + rr;
            if (grow >= lo && grow < hi) cm = fmaxf(cm, acc[mt][nt][rr]);
          }
        cm = fmaxf(cm, __shfl_xor(cm, 16));
        cm = fmaxf(cm, __shfl_xor(cm, 32));
        if (lane < 16) {
          const int col = wcol0 + nt * 16 + lane;
          atomicMax(&cmax[(size_t)col * BB + a], fkey(cm));
        }
      }
    }
  }
}

// ---------------------------------------------------------------------------
// Fold rmax/cmax into logits. grid 256, block 256 (one wave per (a,b))
// ---------------------------------------------------------------------------
__global__ __launch_bounds__(256) void finish_kernel(
    const unsigned* __restrict__ rmax, const unsigned* __restrict__ cmax,
    const float* __restrict__ ls, float* __restrict__ out_logits)
{
  const int tid = threadIdx.x;
  const int w = tid >> 6, lane = tid & 63;
  const int pair = blockIdx.x * 4 + w;
  const int a = pair >> 5, b = pair & 31;
  float s = 0.f;
  #pragma unroll
  for (int k = 0; k < 4; ++k) {
    const int l = lane + k * 64;
    if (l < LL) {
      s += unkey(rmax[(size_t)(a * LL + l) * BB + b]);
      s += unkey(cmax[(size_t)(b * LL + l) * BB + a]);
    }
  }
  #pragma unroll
  for (int o = 1; o < 64; o <<= 1) s += __shfl_xor(s, o);
  if (lane == 0)
    out_logits[a * BB + b] = expf(ls[0]) * s * (0.5f / (float)LL);
}

// ---------------------------------------------------------------------------
// Self-attention: block = (bb, strip of 16 q-rows); 4 waves x 2 heads each.
// probs-mean accumulated in LDS f32 (no global atomics), written once.
// grid (32, 13), block 256
// ---------------------------------------------------------------------------
__global__ __launch_bounds__(256) void attn_kernel(
    const __bf16* __restrict__ qp, const __bf16* __restrict__ kp,
    const __bf16* __restrict__ vpT, float* __restrict__ ctx,
    float* __restrict__ probs_out)
{
  __shared__ __bf16 pr[4][16][PSTR];
  __shared__ float pacc[16][ASTR];

  const int bb = blockIdx.x;
  const int strip = blockIdx.y;
  const int tid = threadIdx.x;
  const int w = tid >> 6, lane = tid & 63;
  const int row0 = strip * 16;

  for (int i = tid; i < 16 * ASTR; i += 256) ((float*)pacc)[i] = 0.f;
  for (int i = lane; i < 16 * 16; i += 64)
    pr[w][i >> 4][208 + (i & 15)] = (__bf16)0.f;
  __syncthreads();

  const int arow = row0 + (lane & 15);
  const bool aval = arow < LL;

  for (int rnd = 0; rnd < 2; ++rnd) {
    const int h = rnd * 4 + w;
    bf16x8 aq[2];
    #pragma unroll
    for (int kc = 0; kc < 2; ++kc) {
      bf16x8 z = {};
      aq[kc] = aval
        ? *(const bf16x8*)&qp[(size_t)(bb * LL + arow) * DD + h * DHH + kc * 32 + (lane >> 4) * 8]
        : z;
    }
    f32x4 s[13] = {};
    #pragma unroll
    for (int nt = 0; nt < 13; ++nt) {
      const int brow = nt * 16 + (lane & 15);
      #pragma unroll
      for (int kc = 0; kc < 2; ++kc) {
        bf16x8 bk = {};
        if (brow < LL)
          bk = *(const bf16x8*)&kp[(size_t)(bb * LL + brow) * DD + h * DHH + kc * 32 + (lane >> 4) * 8];
        s[nt] = MFMA16(aq[kc], bk, s[nt]);
      }
    }
    const int colbase = lane & 15;
    #pragma unroll
    for (int nt = 0; nt < 13; ++nt) {
      const bool cv = (nt * 16 + colbase) < LL;
      #pragma unroll
      for (int rr = 0; rr < 4; ++rr)
        s[nt][rr] = cv ? s[nt][rr] * 0.125f : -1e30f;
    }
    float mx[4], dn[4];
    #pragma unroll
    for (int rr = 0; rr < 4; ++rr) {
      float m = s[0][rr];
      #pragma unroll
      for (int nt = 1; nt < 13; ++nt) m = fmaxf(m, s[nt][rr]);
      m = fmaxf(m, __shfl_xor(m, 1));
      m = fmaxf(m, __shfl_xor(m, 2));
      m = fmaxf(m, __shfl_xor(m, 4));
      m = fmaxf(m, __shfl_xor(m, 8));
      mx[rr] = m;
    }
    #pragma unroll
    for (int nt = 0; nt < 13; ++nt)
      #pragma unroll
      for (int rr = 0; rr < 4; ++rr)
        s[nt][rr] = __expf(s[nt][rr] - mx[rr]);
    #pragma unroll
    for (int rr = 0; rr < 4; ++rr) {
      float d = 0.f;
      #pragma unroll
      for (int nt = 0; nt < 13; ++nt) d += s[nt][rr];
      d += __shfl_xor(d, 1);
      d += __shfl_xor(d, 2);
      d += __shfl_xor(d, 4);
      d += __shfl_xor(d, 8);
      dn[rr] = 1.f / d;
    }
    #pragma unroll
    for (int nt = 0; nt < 13; ++nt)
      #pragma unroll
      for (int rr = 0; rr < 4; ++rr)
        pr[w][(lane >> 4) * 4 + rr][nt * 16 + colbase] = (__bf16)(s[nt][rr] * dn[rr]);
    __syncthreads();   // pr ready for all waves

    // PV: A = pr[w], B = vpT (global, L2-hot)
    f32x4 c4[4] = {};
    #pragma unroll
    for (int kc = 0; kc < 7; ++kc) {
      bf16x8 ap = *(const bf16x8*)&pr[w][lane & 15][kc * 32 + (lane >> 4) * 8];
      #pragma unroll
      for (int dt = 0; dt < 4; ++dt) {
        bf16x8 bv = *(const bf16x8*)&vpT[(size_t)((bb * 8 + h) * 64 + dt * 16 + (lane & 15)) * PVK + kc * 32 + (lane >> 4) * 8];
        c4[dt] = MFMA16(ap, bv, c4[dt]);
      }
    }
    #pragma unroll
    for (int dt = 0; dt < 4; ++dt)
      #pragma unroll
      for (int rr = 0; rr < 4; ++rr) {
        const int qrow = row0 + (lane >> 4) * 4 + rr;
        if (qrow < LL)
          ctx[(size_t)(bb * LL + qrow) * DD + h * DHH + dt * 16 + (lane & 15)] = c4[dt][rr];
      }
    // accumulate probs-mean partial: threads partition 16 x 224
    {
      const int rr_ = tid >> 4;
      const int c0_ = (tid & 15) * 14;
      #pragma unroll
      for (int j = 0; j < 14; ++j) {
        const int c = c0_ + j;
        const float sum = (float)pr[0][rr_][c] + (float)pr[1][rr_][c]
                        + (float)pr[2][rr_][c] + (float)pr[3][rr_][c];
        pacc[rr_][c] += sum * 0.125f;
      }
    }
    __syncthreads();   // done reading pr before next round overwrites
  }

  const int rr_ = tid >> 4;
  const int qrow = row0 + rr_;
  if (qrow < LL) {
    #pragma unroll
    for (int j = 0; j < 13; ++j) {
      const int c = (tid & 15) + j * 16;
      if (c < LL)
        probs_out[((size_t)bb * LL + qrow) * LL + c] = pacc[rr_][c];
    }
  }
}

// ---------------------------------------------------------------------------
// Residual + LayerNorm, in-place on d_out's ctx region. One wave per row.
// ---------------------------------------------------------------------------
__global__ __launch_bounds__(256) void ln_kernel(
    float* __restrict__ ctx, const float* __restrict__ resid,
    const float* __restrict__ gamma, const float* __restrict__ beta)
{
  const int tid = threadIdx.x;
  const int w = tid >> 6, lane = tid & 63;
  const int row = blockIdx.x * 4 + w;
  float* crow = ctx + (size_t)row * DD;
  const float* rrow = resid + (size_t)row * DD;
  const int c = lane * 8;

  float4 a0 = *(const float4*)(crow + c);
  float4 a1 = *(const float4*)(crow + c + 4);
  float4 b0 = *(const float4*)(rrow + c);
  float4 b1 = *(const float4*)(rrow + c + 4);
  float v[8] = {a0.x + b0.x, a0.y + b0.y, a0.z + b0.z, a0.w + b0.w,
                a1.x + b1.x, a1.y + b1.y, a1.z + b1.z, a1.w + b1.w};

  float sum = 0.f;
  #pragma unroll
  for (int j = 0; j < 8; ++j) sum += v[j];
  #pragma unroll
  for (int o = 1; o < 64; o <<= 1) sum += __shfl_xor(sum, o);
  const float mu = sum * (1.f / (float)DD);

  float var = 0.f;
  #pragma unroll
  for (int j = 0; j < 8; ++j) { float d = v[j] - mu; var += d * d; }
  #pragma unroll
  for (int o = 1; o < 64; o <<= 1) var += __shfl_xor(var, o);
  const float rstd = rsqrtf(var * (1.f / (float)DD) + 1e-6f);

  float4 g0 = *(const float4*)(gamma + c);
  float4 g1 = *(const float4*)(gamma + c + 4);
  float4 e0 = *(const float4*)(beta + c);
  float4 e1 = *(const float4*)(beta + c + 4);
  float g[8] = {g0.x, g0.y, g0.z, g0.w, g1.x, g1.y, g1.z, g1.w};
  float e[8] = {e0.x, e0.y, e0.z, e0.w, e1.x, e1.y, e1.z, e1.w};

  float o_[8];
  #pragma unroll
  for (int j = 0; j < 8; ++j) o_[j] = (v[j] - mu) * rstd * g[j] + e[j];
  *(float4*)(crow + c)     = make_float4(o_[0], o_[1], o_[2], o_[3]);
  *(float4*)(crow + c + 4) = make_float4(o_[4], o_[5], o_[6], o_[7]);
}

// ---------------------------------------------------------------------------
extern "C" void kernel_launch(void* const* d_in, const int* in_sizes, int n_in,
                              void* d_out, int out_size, void* d_ws, size_t ws_size,
                              hipStream_t stream)
{
  const float* xq    = (const float*)d_in[0];
  const float* xk    = (const float*)d_in[1];
  const float* xv    = (const float*)d_in[2];
  const float* Wq    = (const float*)d_in[3];
  const float* bq    = (const float*)d_in[4];
  const float* Wk    = (const float*)d_in[5];
  const float* bk    = (const float*)d_in[6];
  const float* Wv    = (const float*)d_in[7];
  const float* bv    = (const float*)d_in[8];
  const float* gamma = (const float*)d_in[9];
  const float* beta  = (const float*)d_in[10];
  const float* ls    = (const float*)d_in[11];

  float* out_ctx    = (float*)d_out;
  float* out_logits = out_ctx + (size_t)BL * DD;   // 3,211,264
  float* out_probs  = out_logits + BB * BB;

  const size_t proj_sz = (size_t)BL * DD;          // 3,211,264 elements (bf16)
  __bf16* qp  = (__bf16*)d_ws;
  __bf16* kp  = qp + proj_sz;
  __bf16* vp  = kp + proj_sz;
  __bf16* vpT = vp + proj_sz;                      // 32*8*64 x 224 bf16
  // rmax/cmax overlap the vp region (vp is dead after transpose_v)
  unsigned* rmax = (unsigned*)vp;                  // 6272*32 u32
  unsigned* cmax = rmax + (size_t)BL * BB;

  proj3_kernel<<<dim3(BL / 64, DD / 64, 3), 256, 0, stream>>>(
      xq, xk, xv, Wq, Wk, Wv, bq, bk, bv, qp, kp, vp);

  transpose_v_kernel<<<dim3(BB * HH, 4), 256, 0, stream>>>(vp, vpT);

  // zero rmax+cmax (contiguous) — key 0 acts as -inf
  hipMemsetAsync(rmax, 0, (size_t)2 * BL * BB * sizeof(unsigned), stream);

  retrieve_kernel<<<2401, 256, 0, stream>>>(qp, kp, rmax, cmax);
  finish_kernel<<<256, 256, 0, stream>>>(rmax, cmax, ls, out_logits);

  attn_kernel<<<dim3(BB, 13), 256, 0, stream>>>(qp, kp, vpT, out_ctx, out_probs);
  ln_kernel<<<BL / 4, 256, 0, stream>>>(out_ctx, xq, gamma, beta);
}

// Round 3
// 242.985 us; speedup vs baseline: 1.5925x; 1.2399x over previous
//
#include <hip/hip_runtime.h>
#include <hip/hip_bf16.h>

#define BB 32
#define LL 196
#define DD 512
#define HH 8
#define DHH 64
#define BL (BB*LL)   // 6272
#define PVK 224      // padded m-dim for PV (7 * 32)
#define PSTR 236     // pr LDS stride (bf16)
#define ASTR 232     // pacc LDS stride (f32)

typedef __bf16 bf16x8 __attribute__((ext_vector_type(8)));
typedef float f32x4 __attribute__((ext_vector_type(4)));

#define MFMA16(a,b,c) __builtin_amdgcn_mfma_f32_16x16x32_bf16((a),(b),(c),0,0,0)

#define GLOAD_LDS16(g, l) __builtin_amdgcn_global_load_lds( \
    (const __attribute__((address_space(1))) void*)(g), \
    (__attribute__((address_space(3))) void*)(l), 16, 0, 0)

static __device__ __forceinline__ bf16x8 pack8(float4 v0, float4 v1) {
  bf16x8 o;
  o[0] = (__bf16)v0.x; o[1] = (__bf16)v0.y; o[2] = (__bf16)v0.z; o[3] = (__bf16)v0.w;
  o[4] = (__bf16)v1.x; o[5] = (__bf16)v1.y; o[6] = (__bf16)v1.z; o[7] = (__bf16)v1.w;
  return o;
}

static __device__ __forceinline__ unsigned fkey(float f) {
  unsigned u = __float_as_uint(f);
  return u ^ ((unsigned)((int)u >> 31) | 0x80000000u);
}
static __device__ __forceinline__ float unkey(unsigned k) {
  unsigned u = (k & 0x80000000u) ? (k ^ 0x80000000u) : ~k;
  return __uint_as_float(u);
}

// Stage a 128x64 bf16 tile pair into LDS, linear dest, inverse-swizzled source.
// swoff must be ((tid&7) ^ ((tid>>3)&7)) << 3  (element offset inside a 64-elem row)
#define STAGE_PAIR(SA, SB, abase, bbase) do { \
  const __bf16* aB_ = (abase); const __bf16* bB_ = (bbase); \
  _Pragma("unroll") \
  for (int c_ = 0; c_ < 4; ++c_) { \
    const int p_ = c_ * 256 + tid; \
    GLOAD_LDS16(aB_ + (size_t)(p_ >> 3) * DD + swoff, &SA[p_ * 8]); \
  } \
  _Pragma("unroll") \
  for (int c_ = 0; c_ < 4; ++c_) { \
    const int p_ = c_ * 256 + tid; \
    GLOAD_LDS16(bB_ + (size_t)(p_ >> 3) * DD + swoff, &SB[p_ * 8]); \
  } \
} while (0)

// 16 MFMA K-step on a staged tile pair, swizzled ds_read addressing.
#define COMPUTE_TILE(SA, SB) do { \
  _Pragma("unroll") \
  for (int kc_ = 0; kc_ < 2; ++kc_) { \
    const int q_ = (((kc_ * 4 + (lane >> 4)) ^ (lane & 7)) << 3); \
    bf16x8 af_[4], bf_[4]; \
    _Pragma("unroll") \
    for (int mt_ = 0; mt_ < 4; ++mt_) \
      af_[mt_] = *(const bf16x8*)&SA[(wr + mt_ * 16 + (lane & 15)) * 64 + q_]; \
    _Pragma("unroll") \
    for (int nt_ = 0; nt_ < 4; ++nt_) \
      bf_[nt_] = *(const bf16x8*)&SB[(wc + nt_ * 16 + (lane & 15)) * 64 + q_]; \
    __builtin_amdgcn_s_setprio(1); \
    _Pragma("unroll") \
    for (int mt_ = 0; mt_ < 4; ++mt_) \
      _Pragma("unroll") \
      for (int nt_ = 0; nt_ < 4; ++nt_) \
        acc[mt_][nt_] = MFMA16(af_[mt_], bf_[nt_], acc[mt_][nt_]); \
    __builtin_amdgcn_s_setprio(0); \
  } \
} while (0)

// ---------------------------------------------------------------------------
// f32 -> bf16 bulk convert: X (3 x 6272x512) and W (3 x 512x512)
// grid (1696, 3), block 256; 8 elems/thread
// ---------------------------------------------------------------------------
__global__ __launch_bounds__(256) void cvt_kernel(
    const float* __restrict__ x0, const float* __restrict__ x1, const float* __restrict__ x2,
    const float* __restrict__ w0, const float* __restrict__ w1, const float* __restrict__ w2,
    __bf16* __restrict__ xb, __bf16* __restrict__ wb)
{
  const int z = blockIdx.y;
  const float* src; __bf16* dst; size_t i;
  if (blockIdx.x < 1568) {
    src = (z == 0) ? x0 : (z == 1) ? x1 : x2;
    dst = xb + (size_t)z * 3211264;
    i = (size_t)blockIdx.x * 256 + threadIdx.x;
  } else {
    src = (z == 0) ? w0 : (z == 1) ? w1 : w2;
    dst = wb + (size_t)z * 262144;
    i = (size_t)(blockIdx.x - 1568) * 256 + threadIdx.x;
  }
  const float4* s = (const float4*)(src + i * 8);
  float4 a = s[0], b = s[1];
  *(bf16x8*)(dst + i * 8) = pack8(a, b);
}

// ---------------------------------------------------------------------------
// Projection NT GEMM (bf16 in/out): out[i][o] = sum_c Xb[i][c]*Wb[o][c] + bias[o]
// grid (49, 4, 3), block 256; 128x128 tile, dbuf + swizzle
// ---------------------------------------------------------------------------
__global__ __launch_bounds__(256) void proj_gemm_kernel(
    const __bf16* __restrict__ xb, const __bf16* __restrict__ wb,
    const float* __restrict__ bq, const float* __restrict__ bk, const float* __restrict__ bv,
    __bf16* __restrict__ qp, __bf16* __restrict__ kp, __bf16* __restrict__ vp)
{
  __shared__ __bf16 sA0[128 * 64], sA1[128 * 64];
  __shared__ __bf16 sB0[128 * 64], sB1[128 * 64];

  const int z = blockIdx.z;
  const __bf16* A = xb + (size_t)z * 3211264;
  const __bf16* B = wb + (size_t)z * 262144;
  const float* bias = (z == 0) ? bq : (z == 1) ? bk : bv;
  __bf16* out = (z == 0) ? qp : (z == 1) ? kp : vp;

  const int tid = threadIdx.x;
  const int w = tid >> 6, lane = tid & 63;
  const int wr = (w >> 1) * 64, wc = (w & 1) * 64;
  const int bm = blockIdx.x * 128, bn = blockIdx.y * 128;
  const int swoff = ((tid & 7) ^ ((tid >> 3) & 7)) << 3;

  const __bf16* aP = A + (size_t)bm * DD;
  const __bf16* bP = B + (size_t)bn * DD;

  f32x4 acc[4][4] = {};

  STAGE_PAIR(sA0, sB0, aP, bP);
  __syncthreads();
  #pragma unroll
  for (int kt = 0; kt < 8; kt += 2) {
    if (kt + 1 < 8) STAGE_PAIR(sA1, sB1, aP + (kt + 1) * 64, bP + (kt + 1) * 64);
    COMPUTE_TILE(sA0, sB0);
    __syncthreads();
    if (kt + 2 < 8) STAGE_PAIR(sA0, sB0, aP + (kt + 2) * 64, bP + (kt + 2) * 64);
    COMPUTE_TILE(sA1, sB1);
    __syncthreads();
  }

  #pragma unroll
  for (int mt = 0; mt < 4; ++mt)
    #pragma unroll
    for (int nt = 0; nt < 4; ++nt)
      #pragma unroll
      for (int rr = 0; rr < 4; ++rr) {
        const int row = bm + wr + mt * 16 + (lane >> 4) * 4 + rr;
        const int col = bn + wc + nt * 16 + (lane & 15);
        out[(size_t)row * DD + col] = (__bf16)(acc[mt][nt][rr] + bias[col]);
      }
}

// ---------------------------------------------------------------------------
// V transpose: vp[(bb*196+m)][h*64+d] -> vpT[(bb*8+h)*64+d][m] (m padded to 224)
// grid (256, 4), block 256
// ---------------------------------------------------------------------------
__global__ __launch_bounds__(256) void transpose_v_kernel(
    const __bf16* __restrict__ vp, __bf16* __restrict__ vpT)
{
  __shared__ __bf16 sT[64][72];
  const int bbh = blockIdx.x;
  const int mt = blockIdx.y;
  const int bb = bbh >> 3, h = bbh & 7;
  const int tid = threadIdx.x;
  {
    const int r = tid >> 2, c0 = (tid & 3) * 16;
    const int m = mt * 64 + r;
    bf16x8 z = {};
    bf16x8 v0 = z, v1 = z;
    if (m < LL) {
      const bf16x8* src = (const bf16x8*)&vp[(size_t)(bb * LL + m) * DD + h * DHH + c0];
      v0 = src[0]; v1 = src[1];
    }
    *(bf16x8*)&sT[r][c0]     = v0;
    *(bf16x8*)&sT[r][c0 + 8] = v1;
  }
  __syncthreads();
  {
    const int d = tid >> 2, mc0 = (tid & 3) * 16;
    if (mt * 64 + mc0 < PVK) {
      bf16x8 o0, o1;
      #pragma unroll
      for (int j = 0; j < 8; ++j) { o0[j] = sT[mc0 + j][d]; o1[j] = sT[mc0 + 8 + j][d]; }
      __bf16* dst = vpT + (size_t)(bbh * 64 + d) * PVK + mt * 64 + mc0;
      *(bf16x8*)dst = o0;
      *(bf16x8*)(dst + 8) = o1;
    }
  }
}

// ---------------------------------------------------------------------------
// Retrieve: flat 6272x6272x512 NT GEMM, dbuf + swizzle + fused segment-max
// epilogue (atomicMax on keyed u32 tables). grid 2401, block 256
// ---------------------------------------------------------------------------
__global__ __launch_bounds__(256) void retrieve_kernel(
    const __bf16* __restrict__ qp, const __bf16* __restrict__ kp,
    unsigned* __restrict__ rmax, unsigned* __restrict__ cmax)
{
  __shared__ __bf16 sA0[128 * 64], sA1[128 * 64];
  __shared__ __bf16 sB0[128 * 64], sB1[128 * 64];

  // bijective XCD chunking (2401 = 8*300 + 1) then 7x7 supertile decode
  const int orig = blockIdx.x;
  const int xcd = orig & 7, idx = orig >> 3;
  const int wg = (xcd == 0) ? idx : (301 + (xcd - 1) * 300 + idx);
  const int st = wg / 49, wi = wg % 49;
  const int brow = ((st / 7) * 7 + wi / 7) * 128;
  const int bcol = ((st % 7) * 7 + wi % 7) * 128;

  const int tid = threadIdx.x;
  const int w = tid >> 6, lane = tid & 63;
  const int wr = (w >> 1) * 64, wc = (w & 1) * 64;
  const int swoff = ((tid & 7) ^ ((tid >> 3) & 7)) << 3;

  const __bf16* aP = qp + (size_t)brow * DD;
  const __bf16* bP = kp + (size_t)bcol * DD;

  f32x4 acc[4][4] = {};

  STAGE_PAIR(sA0, sB0, aP, bP);
  __syncthreads();
  #pragma unroll
  for (int kt = 0; kt < 8; kt += 2) {
    if (kt + 1 < 8) STAGE_PAIR(sA1, sB1, aP + (kt + 1) * 64, bP + (kt + 1) * 64);
    COMPUTE_TILE(sA0, sB0);
    __syncthreads();
    if (kt + 2 < 8) STAGE_PAIR(sA0, sB0, aP + (kt + 2) * 64, bP + (kt + 2) * 64);
    COMPUTE_TILE(sA1, sB1);
    __syncthreads();
  }

  const int wcol0 = bcol + wc;
  const int wrow0 = brow + wr;
  // Row-max per 196-col segment (t2v): rmax[b][grow]
  {
    const int b0 = wcol0 / LL, b1 = (wcol0 + 63) / LL;
    for (int b = b0; b <= b1; ++b) {
      const int lo = b * LL, hi = lo + LL;
      #pragma unroll
      for (int mt = 0; mt < 4; ++mt)
        #pragma unroll
        for (int rr = 0; rr < 4; ++rr) {
          float m = -3e38f;
          #pragma unroll
          for (int nt = 0; nt < 4; ++nt) {
            const int col = wcol0 + nt * 16 + (lane & 15);
            if (col >= lo && col < hi) m = fmaxf(m, acc[mt][nt][rr]);
          }
          m = fmaxf(m, __shfl_xor(m, 1));
          m = fmaxf(m, __shfl_xor(m, 2));
          m = fmaxf(m, __shfl_xor(m, 4));
          m = fmaxf(m, __shfl_xor(m, 8));
          if ((lane & 15) == 0) {
            const int grow = wrow0 + mt * 16 + (lane >> 4) * 4 + rr;
            atomicMax(&rmax[(size_t)b * BL + grow], fkey(m));
          }
        }
    }
  }
  // Col-max per 196-row segment (v2t): cmax[a][col]
  {
    const int a0 = wrow0 / LL, a1 = (wrow0 + 63) / LL;
    for (int a = a0; a <= a1; ++a) {
      const int lo = a * LL, hi = lo + LL;
      #pragma unroll
      for (int nt = 0; nt < 4; ++nt) {
        float cm = -3e38f;
        #pragma unroll
        for (int mt = 0; mt < 4; ++mt)
          #pragma unroll
          for (int rr = 0; rr < 4; ++rr) {
            const int grow = wrow0 + mt * 16 + (lane >> 4) * 4 + rr;
            if (grow >= lo && grow < hi) cm = fmaxf(cm, acc[mt][nt][rr]);
          }
        cm = fmaxf(cm, __shfl_xor(cm, 16));
        cm = fmaxf(cm, __shfl_xor(cm, 32));
        if (lane < 16) {
          const int col = wcol0 + nt * 16 + lane;
          atomicMax(&cmax[(size_t)a * BL + col], fkey(cm));
        }
      }
    }
  }
}

// ---------------------------------------------------------------------------
// Fold rmax/cmax into logits. grid 256, block 256 (one wave per (a,b))
// ---------------------------------------------------------------------------
__global__ __launch_bounds__(256) void finish_kernel(
    const unsigned* __restrict__ rmax, const unsigned* __restrict__ cmax,
    const float* __restrict__ ls, float* __restrict__ out_logits)
{
  const int tid = threadIdx.x;
  const int w = tid >> 6, lane = tid & 63;
  const int pair = blockIdx.x * 4 + w;
  const int a = pair >> 5, b = pair & 31;
  float s = 0.f;
  #pragma unroll
  for (int k = 0; k < 4; ++k) {
    const int l = lane + k * 64;
    if (l < LL) {
      s += unkey(rmax[(size_t)b * BL + a * LL + l]);
      s += unkey(cmax[(size_t)a * BL + b * LL + l]);
    }
  }
  #pragma unroll
  for (int o = 1; o < 64; o <<= 1) s += __shfl_xor(s, o);
  if (lane == 0)
    out_logits[a * BB + b] = expf(ls[0]) * s * (0.5f / (float)LL);
}

// ---------------------------------------------------------------------------
// Self-attention: block = (bb, strip of 16 q-rows); 4 waves x 2 heads each.
// grid (32, 13), block 256
// ---------------------------------------------------------------------------
__global__ __launch_bounds__(256) void attn_kernel(
    const __bf16* __restrict__ qp, const __bf16* __restrict__ kp,
    const __bf16* __restrict__ vpT, float* __restrict__ ctx,
    float* __restrict__ probs_out)
{
  __shared__ __bf16 pr[4][16][PSTR];
  __shared__ float pacc[16][ASTR];

  const int bb = blockIdx.x;
  const int strip = blockIdx.y;
  const int tid = threadIdx.x;
  const int w = tid >> 6, lane = tid & 63;
  const int row0 = strip * 16;

  for (int i = tid; i < 16 * ASTR; i += 256) ((float*)pacc)[i] = 0.f;
  for (int i = lane; i < 16 * 16; i += 64)
    pr[w][i >> 4][208 + (i & 15)] = (__bf16)0.f;
  __syncthreads();

  const int arow = row0 + (lane & 15);
  const bool aval = arow < LL;

  for (int rnd = 0; rnd < 2; ++rnd) {
    const int h = rnd * 4 + w;
    bf16x8 aq[2];
    #pragma unroll
    for (int kc = 0; kc < 2; ++kc) {
      bf16x8 z = {};
      aq[kc] = aval
        ? *(const bf16x8*)&qp[(size_t)(bb * LL + arow) * DD + h * DHH + kc * 32 + (lane >> 4) * 8]
        : z;
    }
    f32x4 s[13] = {};
    __builtin_amdgcn_s_setprio(1);
    #pragma unroll
    for (int nt = 0; nt < 13; ++nt) {
      const int brow = nt * 16 + (lane & 15);
      #pragma unroll
      for (int kc = 0; kc < 2; ++kc) {
        bf16x8 bk = {};
        if (brow < LL)
          bk = *(const bf16x8*)&kp[(size_t)(bb * LL + brow) * DD + h * DHH + kc * 32 + (lane >> 4) * 8];
        s[nt] = MFMA16(aq[kc], bk, s[nt]);
      }
    }
    __builtin_amdgcn_s_setprio(0);
    const int colbase = lane & 15;
    #pragma unroll
    for (int nt = 0; nt < 13; ++nt) {
      const bool cv = (nt * 16 + colbase) < LL;
      #pragma unroll
      for (int rr = 0; rr < 4; ++rr)
        s[nt][rr] = cv ? s[nt][rr] * 0.125f : -1e30f;
    }
    float mx[4], dn[4];
    #pragma unroll
    for (int rr = 0; rr < 4; ++rr) {
      float m = s[0][rr];
      #pragma unroll
      for (int nt = 1; nt < 13; ++nt) m = fmaxf(m, s[nt][rr]);
      m = fmaxf(m, __shfl_xor(m, 1));
      m = fmaxf(m, __shfl_xor(m, 2));
      m = fmaxf(m, __shfl_xor(m, 4));
      m = fmaxf(m, __shfl_xor(m, 8));
      mx[rr] = m;
    }
    #pragma unroll
    for (int nt = 0; nt < 13; ++nt)
      #pragma unroll
      for (int rr = 0; rr < 4; ++rr)
        s[nt][rr] = __expf(s[nt][rr] - mx[rr]);
    #pragma unroll
    for (int rr = 0; rr < 4; ++rr) {
      float d = 0.f;
      #pragma unroll
      for (int nt = 0; nt < 13; ++nt) d += s[nt][rr];
      d += __shfl_xor(d, 1);
      d += __shfl_xor(d, 2);
      d += __shfl_xor(d, 4);
      d += __shfl_xor(d, 8);
      dn[rr] = 1.f / d;
    }
    #pragma unroll
    for (int nt = 0; nt < 13; ++nt)
      #pragma unroll
      for (int rr = 0; rr < 4; ++rr)
        pr[w][(lane >> 4) * 4 + rr][nt * 16 + colbase] = (__bf16)(s[nt][rr] * dn[rr]);
    __syncthreads();

    f32x4 c4[4] = {};
    __builtin_amdgcn_s_setprio(1);
    #pragma unroll
    for (int kc = 0; kc < 7; ++kc) {
      bf16x8 ap = *(const bf16x8*)&pr[w][lane & 15][kc * 32 + (lane >> 4) * 8];
      #pragma unroll
      for (int dt = 0; dt < 4; ++dt) {
        bf16x8 bv = *(const bf16x8*)&vpT[(size_t)((bb * 8 + h) * 64 + dt * 16 + (lane & 15)) * PVK + kc * 32 + (lane >> 4) * 8];
        c4[dt] = MFMA16(ap, bv, c4[dt]);
      }
    }
    __builtin_amdgcn_s_setprio(0);
    #pragma unroll
    for (int dt = 0; dt < 4; ++dt)
      #pragma unroll
      for (int rr = 0; rr < 4; ++rr) {
        const int qrow = row0 + (lane >> 4) * 4 + rr;
        if (qrow < LL)
          ctx[(size_t)(bb * LL + qrow) * DD + h * DHH + dt * 16 + (lane & 15)] = c4[dt][rr];
      }
    {
      const int rr_ = tid >> 4;
      const int c0_ = (tid & 15) * 14;
      #pragma unroll
      for (int j = 0; j < 14; ++j) {
        const int c = c0_ + j;
        const float sum = (float)pr[0][rr_][c] + (float)pr[1][rr_][c]
                        + (float)pr[2][rr_][c] + (float)pr[3][rr_][c];
        pacc[rr_][c] += sum * 0.125f;
      }
    }
    __syncthreads();
  }

  const int rr_ = tid >> 4;
  const int qrow = row0 + rr_;
  if (qrow < LL) {
    #pragma unroll
    for (int j = 0; j < 13; ++j) {
      const int c = (tid & 15) + j * 16;
      if (c < LL)
        probs_out[((size_t)bb * LL + qrow) * LL + c] = pacc[rr_][c];
    }
  }
}

// ---------------------------------------------------------------------------
// Residual + LayerNorm, in-place on d_out's ctx region. One wave per row.
// ---------------------------------------------------------------------------
__global__ __launch_bounds__(256) void ln_kernel(
    float* __restrict__ ctx, const float* __restrict__ resid,
    const float* __restrict__ gamma, const float* __restrict__ beta)
{
  const int tid = threadIdx.x;
  const int w = tid >> 6, lane = tid & 63;
  const int row = blockIdx.x * 4 + w;
  float* crow = ctx + (size_t)row * DD;
  const float* rrow = resid + (size_t)row * DD;
  const int c = lane * 8;

  float4 a0 = *(const float4*)(crow + c);
  float4 a1 = *(const float4*)(crow + c + 4);
  float4 b0 = *(const float4*)(rrow + c);
  float4 b1 = *(const float4*)(rrow + c + 4);
  float v[8] = {a0.x + b0.x, a0.y + b0.y, a0.z + b0.z, a0.w + b0.w,
                a1.x + b1.x, a1.y + b1.y, a1.z + b1.z, a1.w + b1.w};

  float sum = 0.f;
  #pragma unroll
  for (int j = 0; j < 8; ++j) sum += v[j];
  #pragma unroll
  for (int o = 1; o < 64; o <<= 1) sum += __shfl_xor(sum, o);
  const float mu = sum * (1.f / (float)DD);

  float var = 0.f;
  #pragma unroll
  for (int j = 0; j < 8; ++j) { float d = v[j] - mu; var += d * d; }
  #pragma unroll
  for (int o = 1; o < 64; o <<= 1) var += __shfl_xor(var, o);
  const float rstd = rsqrtf(var * (1.f / (float)DD) + 1e-6f);

  float4 g0 = *(const float4*)(gamma + c);
  float4 g1 = *(const float4*)(gamma + c + 4);
  float4 e0 = *(const float4*)(beta + c);
  float4 e1 = *(const float4*)(beta + c + 4);
  float g[8] = {g0.x, g0.y, g0.z, g0.w, g1.x, g1.y, g1.z, g1.w};
  float e[8] = {e0.x, e0.y, e0.z, e0.w, e1.x, e1.y, e1.z, e1.w};

  float o_[8];
  #pragma unroll
  for (int j = 0; j < 8; ++j) o_[j] = (v[j] - mu) * rstd * g[j] + e[j];
  *(float4*)(crow + c)     = make_float4(o_[0], o_[1], o_[2], o_[3]);
  *(float4*)(crow + c + 4) = make_float4(o_[4], o_[5], o_[6], o_[7]);
}

// ---------------------------------------------------------------------------
extern "C" void kernel_launch(void* const* d_in, const int* in_sizes, int n_in,
                              void* d_out, int out_size, void* d_ws, size_t ws_size,
                              hipStream_t stream)
{
  const float* xq    = (const float*)d_in[0];
  const float* xk    = (const float*)d_in[1];
  const float* xv    = (const float*)d_in[2];
  const float* Wq    = (const float*)d_in[3];
  const float* bq    = (const float*)d_in[4];
  const float* Wk    = (const float*)d_in[5];
  const float* bk    = (const float*)d_in[6];
  const float* Wv    = (const float*)d_in[7];
  const float* bv    = (const float*)d_in[8];
  const float* gamma = (const float*)d_in[9];
  const float* beta  = (const float*)d_in[10];
  const float* ls    = (const float*)d_in[11];

  float* out_ctx    = (float*)d_out;
  float* out_logits = out_ctx + (size_t)BL * DD;
  float* out_probs  = out_logits + BB * BB;

  const size_t xsz = (size_t)BL * DD;   // 3,211,264
  const size_t wsz = (size_t)DD * DD;   // 262,144
  __bf16* xb = (__bf16*)d_ws;           // 3 * xsz
  __bf16* wb = xb + 3 * xsz;            // 3 * wsz
  __bf16* qp = wb + 3 * wsz;
  __bf16* kp = qp + xsz;
  __bf16* vp = kp + xsz;
  // xb region is dead after proj_gemm: reuse it for vpT and rmax/cmax
  __bf16* vpT = xb;                                  // 16384 * 224 = 3,670,016 elems
  unsigned* rmax = (unsigned*)(xb + 3670016);        // 6272*32 u32
  unsigned* cmax = rmax + (size_t)BB * BL;

  cvt_kernel<<<dim3(1696, 3), 256, 0, stream>>>(xq, xk, xv, Wq, Wk, Wv, xb, wb);

  proj_gemm_kernel<<<dim3(49, 4, 3), 256, 0, stream>>>(xb, wb, bq, bk, bv, qp, kp, vp);

  transpose_v_kernel<<<dim3(BB * HH, 4), 256, 0, stream>>>(vp, vpT);

  hipMemsetAsync(rmax, 0, (size_t)2 * BB * BL * sizeof(unsigned), stream);

  retrieve_kernel<<<2401, 256, 0, stream>>>(qp, kp, rmax, cmax);
  finish_kernel<<<256, 256, 0, stream>>>(rmax, cmax, ls, out_logits);

  attn_kernel<<<dim3(BB, 13), 256, 0, stream>>>(qp, kp, vpT, out_ctx, out_probs);
  ln_kernel<<<BL / 4, 256, 0, stream>>>(out_ctx, xq, gamma, beta);
}

// Round 4
// 237.676 us; speedup vs baseline: 1.6281x; 1.0223x over previous
//
#include <hip/hip_runtime.h>
#include <hip/hip_bf16.h>

#define BB 32
#define LL 196
#define DD 512
#define HH 8
#define DHH 64
#define BL (BB*LL)   // 6272
#define PVK 224      // padded m-dim for PV (7 * 32)
#define PSTR 236     // pr LDS stride (bf16)

typedef __bf16 bf16x8 __attribute__((ext_vector_type(8)));
typedef float f32x4 __attribute__((ext_vector_type(4)));

#define MFMA16(a,b,c) __builtin_amdgcn_mfma_f32_16x16x32_bf16((a),(b),(c),0,0,0)

#define GLOAD_LDS16(g, l) __builtin_amdgcn_global_load_lds( \
    (const __attribute__((address_space(1))) void*)(g), \
    (__attribute__((address_space(3))) void*)(l), 16, 0, 0)

static __device__ __forceinline__ bf16x8 pack8(float4 v0, float4 v1) {
  bf16x8 o;
  o[0] = (__bf16)v0.x; o[1] = (__bf16)v0.y; o[2] = (__bf16)v0.z; o[3] = (__bf16)v0.w;
  o[4] = (__bf16)v1.x; o[5] = (__bf16)v1.y; o[6] = (__bf16)v1.z; o[7] = (__bf16)v1.w;
  return o;
}

static __device__ __forceinline__ unsigned fkey(float f) {
  unsigned u = __float_as_uint(f);
  return u ^ ((unsigned)((int)u >> 31) | 0x80000000u);
}
static __device__ __forceinline__ float unkey(unsigned k) {
  unsigned u = (k & 0x80000000u) ? (k ^ 0x80000000u) : ~k;
  return __uint_as_float(u);
}

// Stage a 128x64 bf16 tile pair into LDS, linear dest, inverse-swizzled source.
// swoff must be ((tid&7) ^ ((tid>>3)&7)) << 3  (element offset inside a 64-elem row)
#define STAGE_PAIR(SA, SB, abase, bbase) do { \
  const __bf16* aB_ = (abase); const __bf16* bB_ = (bbase); \
  _Pragma("unroll") \
  for (int c_ = 0; c_ < 4; ++c_) { \
    const int p_ = c_ * 256 + tid; \
    GLOAD_LDS16(aB_ + (size_t)(p_ >> 3) * DD + swoff, &SA[p_ * 8]); \
  } \
  _Pragma("unroll") \
  for (int c_ = 0; c_ < 4; ++c_) { \
    const int p_ = c_ * 256 + tid; \
    GLOAD_LDS16(bB_ + (size_t)(p_ >> 3) * DD + swoff, &SB[p_ * 8]); \
  } \
} while (0)

// 16 MFMA K-step on a staged tile pair, swizzled ds_read addressing.
#define COMPUTE_TILE(SA, SB) do { \
  _Pragma("unroll") \
  for (int kc_ = 0; kc_ < 2; ++kc_) { \
    const int q_ = (((kc_ * 4 + (lane >> 4)) ^ (lane & 7)) << 3); \
    bf16x8 af_[4], bf_[4]; \
    _Pragma("unroll") \
    for (int mt_ = 0; mt_ < 4; ++mt_) \
      af_[mt_] = *(const bf16x8*)&SA[(wr + mt_ * 16 + (lane & 15)) * 64 + q_]; \
    _Pragma("unroll") \
    for (int nt_ = 0; nt_ < 4; ++nt_) \
      bf_[nt_] = *(const bf16x8*)&SB[(wc + nt_ * 16 + (lane & 15)) * 64 + q_]; \
    _Pragma("unroll") \
    for (int mt_ = 0; mt_ < 4; ++mt_) \
      _Pragma("unroll") \
      for (int nt_ = 0; nt_ < 4; ++nt_) \
        acc[mt_][nt_] = MFMA16(af_[mt_], bf_[nt_], acc[mt_][nt_]); \
  } \
} while (0)

// ---------------------------------------------------------------------------
// f32 -> bf16 bulk convert: X (3 x 6272x512) and W (3 x 512x512)
// grid (1696, 3), block 256; 8 elems/thread
// ---------------------------------------------------------------------------
__global__ __launch_bounds__(256) void cvt_kernel(
    const float* __restrict__ x0, const float* __restrict__ x1, const float* __restrict__ x2,
    const float* __restrict__ w0, const float* __restrict__ w1, const float* __restrict__ w2,
    __bf16* __restrict__ xb, __bf16* __restrict__ wb)
{
  const int z = blockIdx.y;
  const float* src; __bf16* dst; size_t i;
  if (blockIdx.x < 1568) {
    src = (z == 0) ? x0 : (z == 1) ? x1 : x2;
    dst = xb + (size_t)z * 3211264;
    i = (size_t)blockIdx.x * 256 + threadIdx.x;
  } else {
    src = (z == 0) ? w0 : (z == 1) ? w1 : w2;
    dst = wb + (size_t)z * 262144;
    i = (size_t)(blockIdx.x - 1568) * 256 + threadIdx.x;
  }
  const float4* s = (const float4*)(src + i * 8);
  float4 a = s[0], b = s[1];
  *(bf16x8*)(dst + i * 8) = pack8(a, b);
}

// ---------------------------------------------------------------------------
// Projection NT GEMM (bf16 in/out): out[i][o] = sum_c Xb[i][c]*Wb[o][c] + bias[o]
// grid (49, 4, 3), block 256; 128x128 tile, single-buffer m97 structure
// ---------------------------------------------------------------------------
__global__ __launch_bounds__(256) void proj_gemm_kernel(
    const __bf16* __restrict__ xb, const __bf16* __restrict__ wb,
    const float* __restrict__ bq, const float* __restrict__ bk, const float* __restrict__ bv,
    __bf16* __restrict__ qp, __bf16* __restrict__ kp, __bf16* __restrict__ vp)
{
  __shared__ __bf16 sA[128 * 64];
  __shared__ __bf16 sB[128 * 64];

  const int z = blockIdx.z;
  const __bf16* A = xb + (size_t)z * 3211264;
  const __bf16* B = wb + (size_t)z * 262144;
  const float* bias = (z == 0) ? bq : (z == 1) ? bk : bv;
  __bf16* out = (z == 0) ? qp : (z == 1) ? kp : vp;

  const int tid = threadIdx.x;
  const int w = tid >> 6, lane = tid & 63;
  const int wr = (w >> 1) * 64, wc = (w & 1) * 64;
  const int bm = blockIdx.x * 128, bn = blockIdx.y * 128;
  const int swoff = ((tid & 7) ^ ((tid >> 3) & 7)) << 3;

  const __bf16* aP = A + (size_t)bm * DD;
  const __bf16* bP = B + (size_t)bn * DD;

  f32x4 acc[4][4] = {};

  #pragma unroll
  for (int kt = 0; kt < 8; ++kt) {
    STAGE_PAIR(sA, sB, aP + kt * 64, bP + kt * 64);
    __syncthreads();
    COMPUTE_TILE(sA, sB);
    __syncthreads();
  }

  #pragma unroll
  for (int mt = 0; mt < 4; ++mt)
    #pragma unroll
    for (int nt = 0; nt < 4; ++nt)
      #pragma unroll
      for (int rr = 0; rr < 4; ++rr) {
        const int row = bm + wr + mt * 16 + (lane >> 4) * 4 + rr;
        const int col = bn + wc + nt * 16 + (lane & 15);
        out[(size_t)row * DD + col] = (__bf16)(acc[mt][nt][rr] + bias[col]);
      }
}

// ---------------------------------------------------------------------------
// V transpose: vp[(bb*196+m)][h*64+d] -> vpT[(bb*8+h)*64+d][m] (m padded to 224)
// grid (256, 4), block 256
// ---------------------------------------------------------------------------
__global__ __launch_bounds__(256) void transpose_v_kernel(
    const __bf16* __restrict__ vp, __bf16* __restrict__ vpT)
{
  __shared__ __bf16 sT[64][72];
  const int bbh = blockIdx.x;
  const int mt = blockIdx.y;
  const int bb = bbh >> 3, h = bbh & 7;
  const int tid = threadIdx.x;
  {
    const int r = tid >> 2, c0 = (tid & 3) * 16;
    const int m = mt * 64 + r;
    bf16x8 z = {};
    bf16x8 v0 = z, v1 = z;
    if (m < LL) {
      const bf16x8* src = (const bf16x8*)&vp[(size_t)(bb * LL + m) * DD + h * DHH + c0];
      v0 = src[0]; v1 = src[1];
    }
    *(bf16x8*)&sT[r][c0]     = v0;
    *(bf16x8*)&sT[r][c0 + 8] = v1;
  }
  __syncthreads();
  {
    const int d = tid >> 2, mc0 = (tid & 3) * 16;
    if (mt * 64 + mc0 < PVK) {
      bf16x8 o0, o1;
      #pragma unroll
      for (int j = 0; j < 8; ++j) { o0[j] = sT[mc0 + j][d]; o1[j] = sT[mc0 + 8 + j][d]; }
      __bf16* dst = vpT + (size_t)(bbh * 64 + d) * PVK + mt * 64 + mc0;
      *(bf16x8*)dst = o0;
      *(bf16x8*)(dst + 8) = o1;
    }
  }
}

// ---------------------------------------------------------------------------
// Retrieve: flat 6272x6272x512 NT GEMM, single-buffer m97 structure + swizzle
// + fused segment-max epilogue (atomicMax on keyed u32 tables).
// grid 2401, block 256
// ---------------------------------------------------------------------------
__global__ __launch_bounds__(256) void retrieve_kernel(
    const __bf16* __restrict__ qp, const __bf16* __restrict__ kp,
    unsigned* __restrict__ rmax, unsigned* __restrict__ cmax)
{
  __shared__ __bf16 sA[128 * 64];
  __shared__ __bf16 sB[128 * 64];

  // bijective XCD chunking (2401 = 8*300 + 1) then 7x7 supertile decode
  const int orig = blockIdx.x;
  const int xcd = orig & 7, idx = orig >> 3;
  const int wg = (xcd == 0) ? idx : (301 + (xcd - 1) * 300 + idx);
  const int st = wg / 49, wi = wg % 49;
  const int brow = ((st / 7) * 7 + wi / 7) * 128;
  const int bcol = ((st % 7) * 7 + wi % 7) * 128;

  const int tid = threadIdx.x;
  const int w = tid >> 6, lane = tid & 63;
  const int wr = (w >> 1) * 64, wc = (w & 1) * 64;
  const int swoff = ((tid & 7) ^ ((tid >> 3) & 7)) << 3;

  const __bf16* aP = qp + (size_t)brow * DD;
  const __bf16* bP = kp + (size_t)bcol * DD;

  f32x4 acc[4][4] = {};

  #pragma unroll
  for (int kt = 0; kt < 8; ++kt) {
    STAGE_PAIR(sA, sB, aP + kt * 64, bP + kt * 64);
    __syncthreads();
    COMPUTE_TILE(sA, sB);
    __syncthreads();
  }

  const int wcol0 = bcol + wc;
  const int wrow0 = brow + wr;
  // Row-max per 196-col segment (t2v): rmax[b][grow]
  {
    const int b0 = wcol0 / LL, b1 = (wcol0 + 63) / LL;
    for (int b = b0; b <= b1; ++b) {
      const int lo = b * LL, hi = lo + LL;
      #pragma unroll
      for (int mt = 0; mt < 4; ++mt)
        #pragma unroll
        for (int rr = 0; rr < 4; ++rr) {
          float m = -3e38f;
          #pragma unroll
          for (int nt = 0; nt < 4; ++nt) {
            const int col = wcol0 + nt * 16 + (lane & 15);
            if (col >= lo && col < hi) m = fmaxf(m, acc[mt][nt][rr]);
          }
          m = fmaxf(m, __shfl_xor(m, 1));
          m = fmaxf(m, __shfl_xor(m, 2));
          m = fmaxf(m, __shfl_xor(m, 4));
          m = fmaxf(m, __shfl_xor(m, 8));
          if ((lane & 15) == 0) {
            const int grow = wrow0 + mt * 16 + (lane >> 4) * 4 + rr;
            atomicMax(&rmax[(size_t)b * BL + grow], fkey(m));
          }
        }
    }
  }
  // Col-max per 196-row segment (v2t): cmax[a][col]
  {
    const int a0 = wrow0 / LL, a1 = (wrow0 + 63) / LL;
    for (int a = a0; a <= a1; ++a) {
      const int lo = a * LL, hi = lo + LL;
      #pragma unroll
      for (int nt = 0; nt < 4; ++nt) {
        float cm = -3e38f;
        #pragma unroll
        for (int mt = 0; mt < 4; ++mt)
          #pragma unroll
          for (int rr = 0; rr < 4; ++rr) {
            const int grow = wrow0 + mt * 16 + (lane >> 4) * 4 + rr;
            if (grow >= lo && grow < hi) cm = fmaxf(cm, acc[mt][nt][rr]);
          }
        cm = fmaxf(cm, __shfl_xor(cm, 16));
        cm = fmaxf(cm, __shfl_xor(cm, 32));
        if (lane < 16) {
          const int col = wcol0 + nt * 16 + lane;
          atomicMax(&cmax[(size_t)a * BL + col], fkey(cm));
        }
      }
    }
  }
}

// ---------------------------------------------------------------------------
// Fold rmax/cmax into logits. grid 256, block 256 (one wave per (a,b))
// ---------------------------------------------------------------------------
__global__ __launch_bounds__(256) void finish_kernel(
    const unsigned* __restrict__ rmax, const unsigned* __restrict__ cmax,
    const float* __restrict__ ls, float* __restrict__ out_logits)
{
  const int tid = threadIdx.x;
  const int w = tid >> 6, lane = tid & 63;
  const int pair = blockIdx.x * 4 + w;
  const int a = pair >> 5, b = pair & 31;
  float s = 0.f;
  #pragma unroll
  for (int k = 0; k < 4; ++k) {
    const int l = lane + k * 64;
    if (l < LL) {
      s += unkey(rmax[(size_t)b * BL + a * LL + l]);
      s += unkey(cmax[(size_t)a * BL + b * LL + l]);
    }
  }
  #pragma unroll
  for (int o = 1; o < 64; o <<= 1) s += __shfl_xor(s, o);
  if (lane == 0)
    out_logits[a * BB + b] = expf(ls[0]) * s * (0.5f / (float)LL);
}

// ---------------------------------------------------------------------------
// Self-attention: block = (bb, strip of 16 q-rows); 8 waves = 1 head each,
// single pass. probs-mean written directly (no atomics, no pacc LDS).
// grid (32, 13), block 512
// ---------------------------------------------------------------------------
__global__ __launch_bounds__(512) void attn_kernel(
    const __bf16* __restrict__ qp, const __bf16* __restrict__ kp,
    const __bf16* __restrict__ vpT, float* __restrict__ ctx,
    float* __restrict__ probs_out)
{
  __shared__ __bf16 pr[8][16][PSTR];

  const int bb = blockIdx.x;
  const int strip = blockIdx.y;
  const int tid = threadIdx.x;
  const int w = tid >> 6, lane = tid & 63;   // w == head
  const int h = w;
  const int row0 = strip * 16;

  // zero the PV-padding columns 208..223 of this wave's strip
  for (int i = lane; i < 256; i += 64)
    pr[w][i >> 4][208 + (i & 15)] = (__bf16)0.f;

  const int arow = row0 + (lane & 15);
  const bool aval = arow < LL;

  bf16x8 aq[2];
  #pragma unroll
  for (int kc = 0; kc < 2; ++kc) {
    bf16x8 z = {};
    aq[kc] = aval
      ? *(const bf16x8*)&qp[(size_t)(bb * LL + arow) * DD + h * DHH + kc * 32 + (lane >> 4) * 8]
      : z;
  }
  f32x4 s[13] = {};
  __builtin_amdgcn_s_setprio(1);
  #pragma unroll
  for (int nt = 0; nt < 13; ++nt) {
    const int brow = nt * 16 + (lane & 15);
    #pragma unroll
    for (int kc = 0; kc < 2; ++kc) {
      bf16x8 bk = {};
      if (brow < LL)
        bk = *(const bf16x8*)&kp[(size_t)(bb * LL + brow) * DD + h * DHH + kc * 32 + (lane >> 4) * 8];
      s[nt] = MFMA16(aq[kc], bk, s[nt]);
    }
  }
  __builtin_amdgcn_s_setprio(0);

  const int colbase = lane & 15;
  #pragma unroll
  for (int nt = 0; nt < 13; ++nt) {
    const bool cv = (nt * 16 + colbase) < LL;
    #pragma unroll
    for (int rr = 0; rr < 4; ++rr)
      s[nt][rr] = cv ? s[nt][rr] * 0.125f : -1e30f;
  }
  float mx[4], dn[4];
  #pragma unroll
  for (int rr = 0; rr < 4; ++rr) {
    float m = s[0][rr];
    #pragma unroll
    for (int nt = 1; nt < 13; ++nt) m = fmaxf(m, s[nt][rr]);
    m = fmaxf(m, __shfl_xor(m, 1));
    m = fmaxf(m, __shfl_xor(m, 2));
    m = fmaxf(m, __shfl_xor(m, 4));
    m = fmaxf(m, __shfl_xor(m, 8));
    mx[rr] = m;
  }
  #pragma unroll
  for (int nt = 0; nt < 13; ++nt)
    #pragma unroll
    for (int rr = 0; rr < 4; ++rr)
      s[nt][rr] = __expf(s[nt][rr] - mx[rr]);
  #pragma unroll
  for (int rr = 0; rr < 4; ++rr) {
    float d = 0.f;
    #pragma unroll
    for (int nt = 0; nt < 13; ++nt) d += s[nt][rr];
    d += __shfl_xor(d, 1);
    d += __shfl_xor(d, 2);
    d += __shfl_xor(d, 4);
    d += __shfl_xor(d, 8);
    dn[rr] = 1.f / d;
  }
  #pragma unroll
  for (int nt = 0; nt < 13; ++nt)
    #pragma unroll
    for (int rr = 0; rr < 4; ++rr)
      pr[w][(lane >> 4) * 4 + rr][nt * 16 + colbase] = (__bf16)(s[nt][rr] * dn[rr]);
  __syncthreads();

  // PV: A = pr[w], B = vpT (global, L2-hot)
  f32x4 c4[4] = {};
  __builtin_amdgcn_s_setprio(1);
  #pragma unroll
  for (int kc = 0; kc < 7; ++kc) {
    bf16x8 ap = *(const bf16x8*)&pr[w][lane & 15][kc * 32 + (lane >> 4) * 8];
    #pragma unroll
    for (int dt = 0; dt < 4; ++dt) {
      bf16x8 bv = *(const bf16x8*)&vpT[(size_t)((bb * 8 + h) * 64 + dt * 16 + (lane & 15)) * PVK + kc * 32 + (lane >> 4) * 8];
      c4[dt] = MFMA16(ap, bv, c4[dt]);
    }
  }
  __builtin_amdgcn_s_setprio(0);
  #pragma unroll
  for (int dt = 0; dt < 4; ++dt)
    #pragma unroll
    for (int rr = 0; rr < 4; ++rr) {
      const int qrow = row0 + (lane >> 4) * 4 + rr;
      if (qrow < LL)
        ctx[(size_t)(bb * LL + qrow) * DD + h * DHH + dt * 16 + (lane & 15)] = c4[dt][rr];
    }

  // probs-mean: 512 threads partition 16 rows x 224 cols (7 cols/thread)
  {
    const int rr_ = tid >> 5;
    const int c0_ = (tid & 31) * 7;
    const int qrow = row0 + rr_;
    if (qrow < LL) {
      #pragma unroll
      for (int j = 0; j < 7; ++j) {
        const int c = c0_ + j;
        if (c < LL) {
          float sum = 0.f;
          #pragma unroll
          for (int ww = 0; ww < 8; ++ww) sum += (float)pr[ww][rr_][c];
          probs_out[((size_t)bb * LL + qrow) * LL + c] = sum * 0.125f;
        }
      }
    }
  }
}

// ---------------------------------------------------------------------------
// Residual + LayerNorm, in-place on d_out's ctx region. One wave per row.
// ---------------------------------------------------------------------------
__global__ __launch_bounds__(256) void ln_kernel(
    float* __restrict__ ctx, const float* __restrict__ resid,
    const float* __restrict__ gamma, const float* __restrict__ beta)
{
  const int tid = threadIdx.x;
  const int w = tid >> 6, lane = tid & 63;
  const int row = blockIdx.x * 4 + w;
  float* crow = ctx + (size_t)row * DD;
  const float* rrow = resid + (size_t)row * DD;
  const int c = lane * 8;

  float4 a0 = *(const float4*)(crow + c);
  float4 a1 = *(const float4*)(crow + c + 4);
  float4 b0 = *(const float4*)(rrow + c);
  float4 b1 = *(const float4*)(rrow + c + 4);
  float v[8] = {a0.x + b0.x, a0.y + b0.y, a0.z + b0.z, a0.w + b0.w,
                a1.x + b1.x, a1.y + b1.y, a1.z + b1.z, a1.w + b1.w};

  float sum = 0.f;
  #pragma unroll
  for (int j = 0; j < 8; ++j) sum += v[j];
  #pragma unroll
  for (int o = 1; o < 64; o <<= 1) sum += __shfl_xor(sum, o);
  const float mu = sum * (1.f / (float)DD);

  float var = 0.f;
  #pragma unroll
  for (int j = 0; j < 8; ++j) { float d = v[j] - mu; var += d * d; }
  #pragma unroll
  for (int o = 1; o < 64; o <<= 1) var += __shfl_xor(var, o);
  const float rstd = rsqrtf(var * (1.f / (float)DD) + 1e-6f);

  float4 g0 = *(const float4*)(gamma + c);
  float4 g1 = *(const float4*)(gamma + c + 4);
  float4 e0 = *(const float4*)(beta + c);
  float4 e1 = *(const float4*)(beta + c + 4);
  float g[8] = {g0.x, g0.y, g0.z, g0.w, g1.x, g1.y, g1.z, g1.w};
  float e[8] = {e0.x, e0.y, e0.z, e0.w, e1.x, e1.y, e1.z, e1.w};

  float o_[8];
  #pragma unroll
  for (int j = 0; j < 8; ++j) o_[j] = (v[j] - mu) * rstd * g[j] + e[j];
  *(float4*)(crow + c)     = make_float4(o_[0], o_[1], o_[2], o_[3]);
  *(float4*)(crow + c + 4) = make_float4(o_[4], o_[5], o_[6], o_[7]);
}

// ---------------------------------------------------------------------------
extern "C" void kernel_launch(void* const* d_in, const int* in_sizes, int n_in,
                              void* d_out, int out_size, void* d_ws, size_t ws_size,
                              hipStream_t stream)
{
  const float* xq    = (const float*)d_in[0];
  const float* xk    = (const float*)d_in[1];
  const float* xv    = (const float*)d_in[2];
  const float* Wq    = (const float*)d_in[3];
  const float* bq    = (const float*)d_in[4];
  const float* Wk    = (const float*)d_in[5];
  const float* bk    = (const float*)d_in[6];
  const float* Wv    = (const float*)d_in[7];
  const float* bv    = (const float*)d_in[8];
  const float* gamma = (const float*)d_in[9];
  const float* beta  = (const float*)d_in[10];
  const float* ls    = (const float*)d_in[11];

  float* out_ctx    = (float*)d_out;
  float* out_logits = out_ctx + (size_t)BL * DD;
  float* out_probs  = out_logits + BB * BB;

  const size_t xsz = (size_t)BL * DD;   // 3,211,264
  const size_t wsz = (size_t)DD * DD;   // 262,144
  __bf16* xb = (__bf16*)d_ws;           // 3 * xsz
  __bf16* wb = xb + 3 * xsz;            // 3 * wsz
  __bf16* qp = wb + 3 * wsz;
  __bf16* kp = qp + xsz;
  __bf16* vp = kp + xsz;
  // xb region is dead after proj_gemm: reuse it for vpT and rmax/cmax
  __bf16* vpT = xb;                                  // 16384 * 224 = 3,670,016 elems
  unsigned* rmax = (unsigned*)(xb + 3670016);        // 6272*32 u32
  unsigned* cmax = rmax + (size_t)BB * BL;

  cvt_kernel<<<dim3(1696, 3), 256, 0, stream>>>(xq, xk, xv, Wq, Wk, Wv, xb, wb);

  proj_gemm_kernel<<<dim3(49, 4, 3), 256, 0, stream>>>(xb, wb, bq, bk, bv, qp, kp, vp);

  transpose_v_kernel<<<dim3(BB * HH, 4), 256, 0, stream>>>(vp, vpT);

  hipMemsetAsync(rmax, 0, (size_t)2 * BB * BL * sizeof(unsigned), stream);

  retrieve_kernel<<<2401, 256, 0, stream>>>(qp, kp, rmax, cmax);
  finish_kernel<<<256, 256, 0, stream>>>(rmax, cmax, ls, out_logits);

  attn_kernel<<<dim3(BB, 13), 512, 0, stream>>>(qp, kp, vpT, out_ctx, out_probs);
  ln_kernel<<<BL / 4, 256, 0, stream>>>(out_ctx, xq, gamma, beta);
}